// Round 1
// baseline (87.238 us; speedup 1.0000x reference)
//
#include <hip/hip_runtime.h>
#include <hip/hip_bf16.h>

#define EPS 1e-8f

// Problem constants (from reference): x (32,1,96,96,96) f32, mask (1,1,96,96,96) i32,
// weight (2,1,96,96,96) f32, bias (2,) f32. out (32,2) f32.
constexpr int B_ = 32;
constexpr int N_ = 96 * 96 * 96;      // 884736
constexpr int N4 = N_ / 4;            // 221184 float4 elements
constexpr int TPB = 256;              // 4 waves
constexpr int BPW = 8;                // batches per wave (4 waves * 8 = 32)

// Kernel 1: per-block partial sums.
// Each block: 4 waves. All waves walk the SAME float4-index stream
// (blockIdx.x*64 + lane, stride gridDim.x*64); wave w handles batches
// [w*8, w*8+8). mask/w loads are identical across waves -> L1 hits.
__global__ __launch_bounds__(TPB) void partial_kernel(
    const float4* __restrict__ x,     // (32, N4)
    const int4*   __restrict__ mask,  // (N4)
    const float4* __restrict__ w,     // (2, N4)
    float*        __restrict__ partials)  // (gridDim.x, 64)
{
    const int tid  = threadIdx.x;
    const int wave = tid >> 6;
    const int lane = tid & 63;
    const int b0   = wave * BPW;

    float acc[BPW][2];
#pragma unroll
    for (int bb = 0; bb < BPW; ++bb) { acc[bb][0] = 0.f; acc[bb][1] = 0.f; }

    const int stride = gridDim.x * 64;
    for (int i4 = blockIdx.x * 64 + lane; i4 < N4; i4 += stride) {
        const int4   mi = mask[i4];
        const float4 w0 = w[i4];
        const float4 w1 = w[N4 + i4];
        const float m0 = mi.x ? 1.f : 0.f;
        const float m1 = mi.y ? 1.f : 0.f;
        const float m2 = mi.z ? 1.f : 0.f;
        const float m3 = mi.w ? 1.f : 0.f;
        const float wm0x = w0.x * m0, wm0y = w0.y * m1, wm0z = w0.z * m2, wm0w = w0.w * m3;
        const float wm1x = w1.x * m0, wm1y = w1.y * m1, wm1z = w1.z * m2, wm1w = w1.w * m3;

#pragma unroll
        for (int bb = 0; bb < BPW; ++bb) {
            const float4 xv = x[(size_t)(b0 + bb) * N4 + i4];
            // gate: |x| > EPS ? x : 0   (mask gate already folded into wm)
            const float g0 = (fabsf(xv.x) > EPS) ? xv.x : 0.f;
            const float g1 = (fabsf(xv.y) > EPS) ? xv.y : 0.f;
            const float g2 = (fabsf(xv.z) > EPS) ? xv.z : 0.f;
            const float g3 = (fabsf(xv.w) > EPS) ? xv.w : 0.f;
            float a0 = acc[bb][0], a1 = acc[bb][1];
            a0 = fmaf(g0, wm0x, a0); a0 = fmaf(g1, wm0y, a0);
            a0 = fmaf(g2, wm0z, a0); a0 = fmaf(g3, wm0w, a0);
            a1 = fmaf(g0, wm1x, a1); a1 = fmaf(g1, wm1y, a1);
            a1 = fmaf(g2, wm1z, a1); a1 = fmaf(g3, wm1w, a1);
            acc[bb][0] = a0; acc[bb][1] = a1;
        }
    }

    // Wave butterfly reduce each of the 16 accumulators across 64 lanes.
#pragma unroll
    for (int bb = 0; bb < BPW; ++bb) {
#pragma unroll
        for (int c = 0; c < 2; ++c) {
            float v = acc[bb][c];
            v += __shfl_xor(v, 32, 64);
            v += __shfl_xor(v, 16, 64);
            v += __shfl_xor(v,  8, 64);
            v += __shfl_xor(v,  4, 64);
            v += __shfl_xor(v,  2, 64);
            v += __shfl_xor(v,  1, 64);
            acc[bb][c] = v;   // all lanes now hold the wave sum
        }
    }

    __shared__ float lds[64];   // flat (b*2+c)
    if (lane == 0) {
#pragma unroll
        for (int bb = 0; bb < BPW; ++bb) {
            lds[(b0 + bb) * 2 + 0] = acc[bb][0];
            lds[(b0 + bb) * 2 + 1] = acc[bb][1];
        }
    }
    __syncthreads();
    if (tid < 64) partials[(size_t)blockIdx.x * 64 + tid] = lds[tid];
}

// Kernel 2: deterministic final reduction over nblk partial vectors + bias.
__global__ __launch_bounds__(256) void finalize_kernel(
    const float* __restrict__ partials, const float* __restrict__ bias,
    float* __restrict__ out, int nblk)
{
    __shared__ float red[4][64];
    const int j = threadIdx.x & 63;
    const int q = threadIdx.x >> 6;
    float s = 0.f;
    for (int k = q; k < nblk; k += 4) s += partials[(size_t)k * 64 + j];
    red[q][j] = s;
    __syncthreads();
    if (threadIdx.x < 64) {
        float t = red[0][j] + red[1][j] + red[2][j] + red[3][j];
        out[j] = t + bias[j & 1];   // j = b*2 + c, bias indexed by c
    }
}

extern "C" void kernel_launch(void* const* d_in, const int* in_sizes, int n_in,
                              void* d_out, int out_size, void* d_ws, size_t ws_size,
                              hipStream_t stream) {
    const float4* x    = (const float4*)d_in[0];
    const int4*   mask = (const int4*)d_in[1];
    const float4* w    = (const float4*)d_in[2];
    const float*  bias = (const float*)d_in[3];
    float* out = (float*)d_out;
    float* partials = (float*)d_ws;

    int nblk = 1024;
    const size_t need = (size_t)nblk * 64 * sizeof(float);
    if (ws_size < need) {
        nblk = (int)(ws_size / (64 * sizeof(float)));
        if (nblk < 1) nblk = 1;
    }

    partial_kernel<<<nblk, TPB, 0, stream>>>(x, mask, w, partials);
    finalize_kernel<<<1, 256, 0, stream>>>(partials, bias, out, nblk);
}

// Round 2
// 29.025 us; speedup vs baseline: 3.0056x; 3.0056x over previous
//
#include <hip/hip_runtime.h>
#include <hip/hip_bf16.h>

#define EPS 1e-8f

// Problem constants: x (32,1,96,96,96) f32, mask (1,1,96,96,96) i32,
// weight (2,1,96,96,96) f32, bias (2,) f32. out (32,2) f32.
constexpr int B_ = 32;
constexpr int N_ = 96 * 96 * 96;      // 884736
constexpr int N4 = N_ / 4;            // 221184 float4 elements
constexpr int TPB = 256;              // 4 waves
constexpr int BPW = 8;                // batches per wave (4 waves * 8 = 32)
constexpr int NBLK = 1024;            // 4 blocks/CU on 256 CUs

// Kernel 1: per-block partial sums.
// Each block: 4 waves. All waves walk the SAME float4-index stream
// (blockIdx.x*64 + lane, stride gridDim.x*64); wave w handles batches
// [w*8, w*8+8). mask/w loads are identical across waves -> L1 hits.
// Partials stored TRANSPOSED: partials[slot * NBLK + block] so finalize
// reads each slot as one contiguous 4 KB run.
__global__ __launch_bounds__(TPB) void partial_kernel(
    const float4* __restrict__ x,     // (32, N4)
    const int4*   __restrict__ mask,  // (N4)
    const float4* __restrict__ w,     // (2, N4)
    float*        __restrict__ partials)  // (64, NBLK) transposed
{
    const int tid  = threadIdx.x;
    const int wave = tid >> 6;
    const int lane = tid & 63;
    const int b0   = wave * BPW;

    float acc[BPW][2];
#pragma unroll
    for (int bb = 0; bb < BPW; ++bb) { acc[bb][0] = 0.f; acc[bb][1] = 0.f; }

    const int stride = gridDim.x * 64;
    for (int i4 = blockIdx.x * 64 + lane; i4 < N4; i4 += stride) {
        const int4   mi = mask[i4];
        const float4 w0 = w[i4];
        const float4 w1 = w[N4 + i4];
        const float m0 = mi.x ? 1.f : 0.f;
        const float m1 = mi.y ? 1.f : 0.f;
        const float m2 = mi.z ? 1.f : 0.f;
        const float m3 = mi.w ? 1.f : 0.f;
        const float wm0x = w0.x * m0, wm0y = w0.y * m1, wm0z = w0.z * m2, wm0w = w0.w * m3;
        const float wm1x = w1.x * m0, wm1y = w1.y * m1, wm1z = w1.z * m2, wm1w = w1.w * m3;

#pragma unroll
        for (int bb = 0; bb < BPW; ++bb) {
            const float4 xv = x[(size_t)(b0 + bb) * N4 + i4];
            const float g0 = (fabsf(xv.x) > EPS) ? xv.x : 0.f;
            const float g1 = (fabsf(xv.y) > EPS) ? xv.y : 0.f;
            const float g2 = (fabsf(xv.z) > EPS) ? xv.z : 0.f;
            const float g3 = (fabsf(xv.w) > EPS) ? xv.w : 0.f;
            float a0 = acc[bb][0], a1 = acc[bb][1];
            a0 = fmaf(g0, wm0x, a0); a0 = fmaf(g1, wm0y, a0);
            a0 = fmaf(g2, wm0z, a0); a0 = fmaf(g3, wm0w, a0);
            a1 = fmaf(g0, wm1x, a1); a1 = fmaf(g1, wm1y, a1);
            a1 = fmaf(g2, wm1z, a1); a1 = fmaf(g3, wm1w, a1);
            acc[bb][0] = a0; acc[bb][1] = a1;
        }
    }

    // Wave butterfly reduce each accumulator across 64 lanes.
#pragma unroll
    for (int bb = 0; bb < BPW; ++bb) {
#pragma unroll
        for (int c = 0; c < 2; ++c) {
            float v = acc[bb][c];
            v += __shfl_xor(v, 32, 64);
            v += __shfl_xor(v, 16, 64);
            v += __shfl_xor(v,  8, 64);
            v += __shfl_xor(v,  4, 64);
            v += __shfl_xor(v,  2, 64);
            v += __shfl_xor(v,  1, 64);
            acc[bb][c] = v;
        }
    }

    __shared__ float lds[64];   // flat slot index b*2+c
    if (lane == 0) {
#pragma unroll
        for (int bb = 0; bb < BPW; ++bb) {
            lds[(b0 + bb) * 2 + 0] = acc[bb][0];
            lds[(b0 + bb) * 2 + 1] = acc[bb][1];
        }
    }
    __syncthreads();
    if (tid < 64) partials[(size_t)tid * gridDim.x + blockIdx.x] = lds[tid];
}

// Kernel 2: one block per output slot (64 blocks). Each thread reads exactly
// one float4 of the slot's contiguous NBLK-float run; butterfly + LDS reduce.
__global__ __launch_bounds__(256) void finalize_kernel(
    const float4* __restrict__ partials4,  // (64, nblk4)
    const float*  __restrict__ bias,
    float* __restrict__ out, int nblk4)
{
    const int j    = blockIdx.x;     // slot = b*2 + c
    const int tid  = threadIdx.x;
    const int wave = tid >> 6;
    const int lane = tid & 63;

    float s = 0.f;
    for (int k = tid; k < nblk4; k += 256) {
        const float4 v = partials4[(size_t)j * nblk4 + k];
        s += (v.x + v.y) + (v.z + v.w);
    }
    s += __shfl_xor(s, 32, 64);
    s += __shfl_xor(s, 16, 64);
    s += __shfl_xor(s,  8, 64);
    s += __shfl_xor(s,  4, 64);
    s += __shfl_xor(s,  2, 64);
    s += __shfl_xor(s,  1, 64);

    __shared__ float red[4];
    if (lane == 0) red[wave] = s;
    __syncthreads();
    if (tid == 0)
        out[j] = (red[0] + red[1]) + (red[2] + red[3]) + bias[j & 1];
}

extern "C" void kernel_launch(void* const* d_in, const int* in_sizes, int n_in,
                              void* d_out, int out_size, void* d_ws, size_t ws_size,
                              hipStream_t stream) {
    const float4* x    = (const float4*)d_in[0];
    const int4*   mask = (const int4*)d_in[1];
    const float4* w    = (const float4*)d_in[2];
    const float*  bias = (const float*)d_in[3];
    float* out = (float*)d_out;
    float* partials = (float*)d_ws;

    int nblk = NBLK;
    const size_t need = (size_t)nblk * 64 * sizeof(float);
    if (ws_size < need) {
        nblk = (int)(ws_size / (64 * sizeof(float)));
        if (nblk < 4) nblk = 4;
        nblk &= ~3;  // keep multiple of 4 for float4 finalize
    }

    partial_kernel<<<nblk, TPB, 0, stream>>>(x, mask, w, partials);
    finalize_kernel<<<64, 256, 0, stream>>>((const float4*)partials, bias, out,
                                            nblk / 4);
}